// Round 8
// baseline (147.628 us; speedup 1.0000x reference)
//
#include <hip/hip_runtime.h>
#include <hip/hip_bf16.h>

// GCN layer: out = scatter_add(edge_val * (x @ W^T)[edge_col], edge_row) + bias
// N=50000, E=800000, D=128.
// R8: 3 launches (was 4). cvt_bf16 kernel deleted: gemm reads W fp32 and
// converts per-fragment in-register (784 waves x 64KB W re-read = 50MB L2,
// ~1.4us aggregate; VALU slack absorbs the cvt2s at 3 waves/SIMD). gemm
// block 0 zeroes the bucket cursors (gemm precedes binpass in-stream).
// sortgather carries its <=2 edges/thread in registers across the scan
// (saves the 6.4MB second coarse read). Full-tile fast path in gemm stores.
// ~55us of dur_us is harness poison/restore (256MiB ws fill = 44us) - fixed.

constexpr int D     = 128;
constexpr int NPB   = 64;    // nodes per bucket (dstloc fits in 6 bits)
constexpr int CAP   = 2048;  // bucket capacity; mean load 1024 (+32 sigma)
constexpr int C1    = 3200;  // edges per binpass block (250 blocks at E=800k)
constexpr int BT    = 1024;  // threads per sort-phase block
constexpr int NBMAX = 1024;  // max buckets (one per thread in binpass scan)

// ---- helpers ----
__device__ inline unsigned int bf1(float f) {            // fp32 -> bf16 bits (RNE)
    unsigned int u = __float_as_uint(f);
    return (u + 0x7fffu + ((u >> 16) & 1u)) >> 16;
}
__device__ inline unsigned int cvt2(float a, float b) {  // packed HW cvt (RNE)
    __hip_bfloat162 h = __float22bfloat162_rn(float2{a, b});
    return *reinterpret_cast<unsigned int*>(&h);
}
__device__ inline float bflo(unsigned int u) { return __uint_as_float(u << 16); }
__device__ inline float bfhi(unsigned int u) { return __uint_as_float(u & 0xffff0000u); }

// ---- GEMM: supb[n][o] = bf16( sum_k x[n][k] * W[o][k] ), MFMA 16x16x32 ----
// W read as fp32, converted per-fragment. 2 row-strips/wave share B-frags.
// Block 0 additionally zeroes gcursor[0..nb) for the downstream binpass.
__global__ __launch_bounds__(256) void gemm_mfma_kernel(const float* __restrict__ x,
                                                        const float* __restrict__ W,
                                                        unsigned short* __restrict__ supb,
                                                        int n_nodes,
                                                        int* __restrict__ gcursor, int nb) {
    using frag  = __attribute__((ext_vector_type(8))) short;
    using f32x4 = __attribute__((ext_vector_type(4))) float;
    union FU { uint4 u; frag f; };

    if (blockIdx.x == 0) {
        for (int i = threadIdx.x; i < nb; i += 256) gcursor[i] = 0;
    }

    const int wv = threadIdx.x >> 6;
    const int lane = threadIdx.x & 63;
    const int m = lane & 15, quad = lane >> 4;
    const int row0 = blockIdx.x * 128 + wv * 32;     // strips: row0, row0+16
    const bool full = (row0 + 32 <= n_nodes);
    const int r0 = full ? row0 + m      : min(row0 + m, n_nodes - 1);
    const int r1 = full ? row0 + 16 + m : min(row0 + 16 + m, n_nodes - 1);

    frag a0[4], a1[4];
#pragma unroll
    for (int kf = 0; kf < 4; ++kf) {
        const float4* xp0 = (const float4*)(x + (size_t)r0 * D + kf * 32 + quad * 8);
        float4 p = xp0[0], q = xp0[1];
        FU t;
        t.u.x = cvt2(p.x, p.y); t.u.y = cvt2(p.z, p.w);
        t.u.z = cvt2(q.x, q.y); t.u.w = cvt2(q.z, q.w);
        a0[kf] = t.f;
        const float4* xp1 = (const float4*)(x + (size_t)r1 * D + kf * 32 + quad * 8);
        p = xp1[0]; q = xp1[1];
        t.u.x = cvt2(p.x, p.y); t.u.y = cvt2(p.z, p.w);
        t.u.z = cvt2(q.x, q.y); t.u.w = cvt2(q.z, q.w);
        a1[kf] = t.f;
    }

    f32x4 acc0[8], acc1[8];
#pragma unroll
    for (int ct = 0; ct < 8; ++ct) {
        acc0[ct] = (f32x4){0.f, 0.f, 0.f, 0.f};
        acc1[ct] = (f32x4){0.f, 0.f, 0.f, 0.f};
    }

#pragma unroll
    for (int ct = 0; ct < 8; ++ct) {
        const float* wrow = W + (size_t)(ct * 16 + m) * D;
#pragma unroll
        for (int kf = 0; kf < 4; ++kf) {
            const float4* wp = (const float4*)(wrow + kf * 32 + quad * 8);
            float4 p = wp[0], q = wp[1];
            FU t;
            t.u.x = cvt2(p.x, p.y); t.u.y = cvt2(p.z, p.w);
            t.u.z = cvt2(q.x, q.y); t.u.w = cvt2(q.z, q.w);
            acc0[ct] = __builtin_amdgcn_mfma_f32_16x16x32_bf16(a0[kf], t.f, acc0[ct], 0, 0, 0);
            acc1[ct] = __builtin_amdgcn_mfma_f32_16x16x32_bf16(a1[kf], t.f, acc1[ct], 0, 0, 0);
        }
    }

    if (full) {
#pragma unroll
        for (int ct = 0; ct < 8; ++ct) {
#pragma unroll
            for (int r = 0; r < 4; ++r) {
                int rr0 = row0 + quad * 4 + r;
                supb[(size_t)rr0 * D + ct * 16 + m] = (unsigned short)bf1(acc0[ct][r]);
                supb[(size_t)(rr0 + 16) * D + ct * 16 + m] = (unsigned short)bf1(acc1[ct][r]);
            }
        }
    } else {
#pragma unroll
        for (int ct = 0; ct < 8; ++ct) {
#pragma unroll
            for (int r = 0; r < 4; ++r) {
                int rr0 = row0 + quad * 4 + r;
                if (rr0 < n_nodes)
                    supb[(size_t)rr0 * D + ct * 16 + m] = (unsigned short)bf1(acc0[ct][r]);
                int rr1 = rr0 + 16;
                if (rr1 < n_nodes)
                    supb[(size_t)rr1 * D + ct * 16 + m] = (unsigned short)bf1(acc1[ct][r]);
            }
        }
    }
}

// ---- pass 1: LDS-staged coarse binning (1024 threads, C1=3200) ----
__global__ __launch_bounds__(BT) void binpass_kernel(const int* __restrict__ erow,
                                                     const int* __restrict__ ecol,
                                                     const float* __restrict__ eval,
                                                     int* __restrict__ gcursor,
                                                     int2* __restrict__ coarse,
                                                     int n_edges, int nb) {
    __shared__ int bkcnt[NBMAX];
    __shared__ int bkoff[NBMAX];
    __shared__ int wsum[16];
    __shared__ int gbase[NBMAX];
    __shared__ unsigned short slotbk[C1];
    __shared__ int2 stage[C1];
    const int t = threadIdx.x;
    const int base = blockIdx.x * C1;
    const int m = min(C1, n_edges - base);

    for (int i = t; i < nb; i += BT) bkcnt[i] = 0;
    __syncthreads();

    constexpr int EPT = (C1 + BT - 1) / BT;  // 4 (last partially used)
    int  bk[EPT], rank[EPT];
    int2 pk[EPT];
#pragma unroll
    for (int j = 0; j < EPT; ++j) {
        int i = t + j * BT;              // coalesced
        bk[j] = -1;
        if (i < m) {
            int e = base + i;
            int dst = erow[e];
            int b = dst / NPB;
            bk[j] = b;
            rank[j] = atomicAdd(&bkcnt[b], 1);
            pk[j] = make_int2(ecol[e] | ((dst & (NPB - 1)) << 20),
                              __float_as_int(eval[e]));
        }
    }
    __syncthreads();

    // hierarchical exclusive scan of bkcnt[0..nb): 2 barriers total
    {
        const int w = t >> 6, l = t & 63;
        int v = (t < nb) ? bkcnt[t] : 0;
        int inc = v;                      // 64-lane inclusive shuffle scan
#pragma unroll
        for (int o = 1; o < 64; o <<= 1) {
            int u = __shfl_up(inc, o, 64);
            if (l >= o) inc += u;
        }
        if (l == 63) wsum[w] = inc;
        __syncthreads();
        if (t < 16) {                     // scan the 16 wave totals
            int wv2 = wsum[t];
            int winc = wv2;
#pragma unroll
            for (int o = 1; o < 16; o <<= 1) {
                int u = __shfl_up(winc, o, 16);
                if (t >= o) winc += u;
            }
            wsum[t] = winc - wv2;         // exclusive wave prefix
        }
        __syncthreads();
        if (t < nb) bkoff[t] = inc - v + wsum[w];
    }
    __syncthreads();

    // place into stage (LDS scatter) + record slot->bucket
#pragma unroll
    for (int j = 0; j < EPT; ++j) {
        if (bk[j] >= 0) {
            int s = bkoff[bk[j]] + rank[j];
            stage[s] = pk[j];
            slotbk[s] = (unsigned short)bk[j];
        }
    }
    // reserve global runs: one atomic per non-empty bucket
    if (t < nb) {
        int c = bkcnt[t];
        gbase[t] = (c > 0) ? (t * CAP + atomicAdd(&gcursor[t], c)) : 0;
    }
    __syncthreads();

    // copy runs out (consecutive slots in a bucket -> consecutive global addrs)
    for (int i = t; i < m; i += BT) {
        int b = slotbk[i];
        int p = gbase[b] + (i - bkoff[b]);
        if (p < (b + 1) * CAP) coarse[p] = stage[i];   // clamp: never hit here
    }
}

// ---- pass 2: within-bucket exact sort in LDS + quarter-wave fused gather ----
__global__ __launch_bounds__(BT) void sortgather_kernel(const int* __restrict__ gcursor,
                                                        const int2* __restrict__ coarse,
                                                        const unsigned short* __restrict__ supb,
                                                        const float* __restrict__ bias,
                                                        float* __restrict__ out,
                                                        int n_nodes) {
    __shared__ int ncnt[NPB];
    __shared__ int noff[NPB];
    __shared__ int ncur[NPB];
    __shared__ int2 sorted[CAP];
    const int t = threadIdx.x;
    const int b = blockIdx.x;
    const int node0 = b * NPB;
    const int m = min(gcursor[b], CAP);
    const int2* src = coarse + (size_t)b * CAP;

    if (t < NPB) ncnt[t] = 0;
    __syncthreads();

    // read edges once into registers; count
    constexpr int EPT2 = CAP / BT;        // 2
    int2 ee[EPT2];
    int  dl[EPT2];
#pragma unroll
    for (int j = 0; j < EPT2; ++j) {
        int i = t + j * BT;
        dl[j] = -1;
        if (i < m) {
            ee[j] = src[i];
            dl[j] = (ee[j].x >> 20) & (NPB - 1);
            atomicAdd(&ncnt[dl[j]], 1);
        }
    }
    __syncthreads();

    if (t < NPB) {                        // wave 0: 64-lane inclusive shuffle scan
        int v = ncnt[t];
        int inc = v;
        for (int o = 1; o < NPB; o <<= 1) {
            int u = __shfl_up(inc, o, 64);
            if (t >= o) inc += u;
        }
        noff[t] = inc - v;
        ncur[t] = inc - v;
    }
    __syncthreads();

#pragma unroll
    for (int j = 0; j < EPT2; ++j) {      // place into sorted LDS slots
        if (dl[j] >= 0) {
            int p = atomicAdd(&ncur[dl[j]], 1);
            sorted[p] = make_int2(ee[j].x & 0xFFFFF, ee[j].y);
        }
    }
    __syncthreads();

    // gather: 64 quarter-waves <-> 64 nodes; 16 lanes x 8 cols (uint4 = 8 bf16)
    const int qw = t >> 4;               // dst-local node id, 0..63
    const int l16 = t & 15;              // lane within quarter-wave
    const int node = node0 + qw;
    if (node >= n_nodes) return;
    const int beg = noff[qw];
    const int end = beg + ncnt[qw];

    const float4* b4 = (const float4*)(bias + l16 * 8);
    float4 acc0 = b4[0], acc1 = b4[1];

    int e = beg;
    for (; e + 1 < end; e += 2) {
        int2 d0 = sorted[e], d1 = sorted[e + 1];   // quarter-wave broadcast reads
        uint4 u0 = *(const uint4*)(supb + (size_t)d0.x * D + l16 * 8);
        uint4 u1 = *(const uint4*)(supb + (size_t)d1.x * D + l16 * 8);
        float v0 = __int_as_float(d0.y), v1 = __int_as_float(d1.y);
        acc0.x += v0 * bflo(u0.x) + v1 * bflo(u1.x);
        acc0.y += v0 * bfhi(u0.x) + v1 * bfhi(u1.x);
        acc0.z += v0 * bflo(u0.y) + v1 * bflo(u1.y);
        acc0.w += v0 * bfhi(u0.y) + v1 * bfhi(u1.y);
        acc1.x += v0 * bflo(u0.z) + v1 * bflo(u1.z);
        acc1.y += v0 * bfhi(u0.z) + v1 * bfhi(u1.z);
        acc1.z += v0 * bflo(u0.w) + v1 * bflo(u1.w);
        acc1.w += v0 * bfhi(u0.w) + v1 * bfhi(u1.w);
    }
    if (e < end) {
        int2 d0 = sorted[e];
        uint4 u0 = *(const uint4*)(supb + (size_t)d0.x * D + l16 * 8);
        float v0 = __int_as_float(d0.y);
        acc0.x += v0 * bflo(u0.x); acc0.y += v0 * bfhi(u0.x);
        acc0.z += v0 * bflo(u0.y); acc0.w += v0 * bfhi(u0.y);
        acc1.x += v0 * bflo(u0.z); acc1.y += v0 * bfhi(u0.z);
        acc1.z += v0 * bflo(u0.w); acc1.w += v0 * bfhi(u0.w);
    }
    float4* o4 = (float4*)(out + (size_t)node * D + l16 * 8);
    o4[0] = acc0;
    o4[1] = acc1;
}

// ---- fallback (oversized graphs / tiny ws): atomic path ----
__global__ __launch_bounds__(256) void init_out_kernel(float4* __restrict__ out4,
                                                       const float4* __restrict__ bias4,
                                                       int total4) {
    int i = blockIdx.x * 256 + threadIdx.x;
    if (i < total4) out4[i] = bias4[i & 31];
}

__global__ __launch_bounds__(256) void scatter_fb_kernel(const int* __restrict__ erow,
                                                         const int* __restrict__ ecol,
                                                         const float* __restrict__ eval,
                                                         const unsigned short* __restrict__ supb,
                                                         float* __restrict__ out,
                                                         int n_edges) {
    int e = blockIdx.x * 8 + (threadIdx.x >> 5);
    if (e >= n_edges) return;
    int lane = threadIdx.x & 31;
    int src = ecol[e], dst = erow[e];
    float v = eval[e];
    const unsigned short* sp = supb + (size_t)src * D + lane * 4;
    float* op = out + (size_t)dst * D + lane * 4;
#pragma unroll
    for (int j = 0; j < 4; ++j)
        atomicAdd(op + j, v * __uint_as_float(((unsigned)sp[j]) << 16));
}

static inline size_t align_up(size_t v, size_t a) { return (v + a - 1) & ~(a - 1); }

extern "C" void kernel_launch(void* const* d_in, const int* in_sizes, int n_in,
                              void* d_out, int out_size, void* d_ws, size_t ws_size,
                              hipStream_t stream) {
    const float* x    = (const float*)d_in[0];
    const int*   erow = (const int*)d_in[1];
    const int*   ecol = (const int*)d_in[2];
    const float* eval = (const float*)d_in[3];
    const float* W    = (const float*)d_in[4];
    const float* bias = (const float*)d_in[5];
    float* out = (float*)d_out;

    const int n_nodes = in_sizes[0] / D;
    const int n_edges = in_sizes[1];
    const int nb = (n_nodes + NPB - 1) / NPB;

    char* base = (char*)d_ws;
    size_t off = 0;
    unsigned short* supb = (unsigned short*)(base + off); off = align_up(off + (size_t)n_nodes * D * 2, 256);
    int*  gcursor = (int*)(base + off);  off = align_up(off + (size_t)nb * 4, 256);
    int2* coarse  = (int2*)(base + off); off = align_up(off + (size_t)nb * CAP * 8, 256);

    const bool fast = (n_nodes < (1 << 20)) && (nb <= NBMAX) && (off <= ws_size);

    gemm_mfma_kernel<<<(n_nodes + 127) / 128, 256, 0, stream>>>(
        x, W, supb, n_nodes, gcursor, fast ? nb : 0);

    if (fast) {
        binpass_kernel<<<(n_edges + C1 - 1) / C1, BT, 0, stream>>>(
            erow, ecol, eval, gcursor, coarse, n_edges, nb);
        sortgather_kernel<<<nb, BT, 0, stream>>>(
            gcursor, coarse, supb, bias, out, n_nodes);
    } else {
        int total4 = n_nodes * (D / 4);
        init_out_kernel<<<(total4 + 255) / 256, 256, 0, stream>>>(
            (float4*)out, (const float4*)bias, total4);
        scatter_fb_kernel<<<(n_edges + 7) / 8, 256, 0, stream>>>(
            erow, ecol, eval, supb, out, n_edges);
    }
}

// Round 9
// 142.692 us; speedup vs baseline: 1.0346x; 1.0346x over previous
//
#include <hip/hip_runtime.h>
#include <hip/hip_bf16.h>

// GCN layer: out = scatter_add(edge_val * (x @ W^T)[edge_col], edge_row) + bias
// N=50000, E=800000, D=128.
// R9: revert R8's W-fp32-in-gemm (it re-converted W per wave: +5.3us measured;
// cvt-once kernel + bf16 Wb global reads is the measured-best config). Keep
// R8's sortgather register-carry + full-tile gemm stores. Add 4-edge unroll
// in the gather loop (4 outstanding loads on the L3-latency-bound supb reads).
// ~55us of dur_us is harness poison/restore (256MiB ws fill = 44us) - fixed.

constexpr int D     = 128;
constexpr int NPB   = 64;    // nodes per bucket (dstloc fits in 6 bits)
constexpr int CAP   = 2048;  // bucket capacity; mean load 1024 (+32 sigma)
constexpr int C1    = 3200;  // edges per binpass block (250 blocks at E=800k)
constexpr int BT    = 1024;  // threads per sort-phase block
constexpr int NBMAX = 1024;  // max buckets (one per thread in binpass scan)

// ---- helpers ----
__device__ inline unsigned int bf1(float f) {            // fp32 -> bf16 bits (RNE)
    unsigned int u = __float_as_uint(f);
    return (u + 0x7fffu + ((u >> 16) & 1u)) >> 16;
}
__device__ inline unsigned int cvt2(float a, float b) {  // packed HW cvt (RNE)
    __hip_bfloat162 h = __float22bfloat162_rn(float2{a, b});
    return *reinterpret_cast<unsigned int*>(&h);
}
__device__ inline float bflo(unsigned int u) { return __uint_as_float(u << 16); }
__device__ inline float bfhi(unsigned int u) { return __uint_as_float(u & 0xffff0000u); }

// ---- W -> bf16 once (+ zero the bucket cursors; runs before binpass) ----
__global__ __launch_bounds__(256) void cvt_bf16_kernel(const float* __restrict__ in,
                                                       uint4* __restrict__ out, int n8,
                                                       int* __restrict__ gcursor, int nb) {
    int i = blockIdx.x * 256 + threadIdx.x;
    if (i < nb) gcursor[i] = 0;
    if (i >= n8) return;
    const float4* p = (const float4*)in + (size_t)i * 2;
    float4 a = p[0], b = p[1];
    uint4 r;
    r.x = cvt2(a.x, a.y); r.y = cvt2(a.z, a.w);
    r.z = cvt2(b.x, b.y); r.w = cvt2(b.z, b.w);
    out[i] = r;
}

// ---- GEMM: supb[n][o] = bf16( sum_k x[n][k] * W[o][k] ), MFMA 16x16x32 ----
// 2 row-strips of 16 per wave share every B-fragment; Wb bf16 is L1-resident.
__global__ __launch_bounds__(256) void gemm_mfma_kernel(const float* __restrict__ x,
                                                        const unsigned short* __restrict__ Wb,
                                                        unsigned short* __restrict__ supb,
                                                        int n_nodes) {
    using frag  = __attribute__((ext_vector_type(8))) short;
    using f32x4 = __attribute__((ext_vector_type(4))) float;
    union FU { uint4 u; frag f; };
    const int wv = threadIdx.x >> 6;
    const int lane = threadIdx.x & 63;
    const int m = lane & 15, quad = lane >> 4;
    const int row0 = blockIdx.x * 128 + wv * 32;     // strips: row0, row0+16
    const bool full = (row0 + 32 <= n_nodes);
    const int r0 = full ? row0 + m      : min(row0 + m, n_nodes - 1);
    const int r1 = full ? row0 + 16 + m : min(row0 + 16 + m, n_nodes - 1);

    frag a0[4], a1[4];
#pragma unroll
    for (int kf = 0; kf < 4; ++kf) {
        const float4* xp0 = (const float4*)(x + (size_t)r0 * D + kf * 32 + quad * 8);
        float4 p = xp0[0], q = xp0[1];
        FU t;
        t.u.x = cvt2(p.x, p.y); t.u.y = cvt2(p.z, p.w);
        t.u.z = cvt2(q.x, q.y); t.u.w = cvt2(q.z, q.w);
        a0[kf] = t.f;
        const float4* xp1 = (const float4*)(x + (size_t)r1 * D + kf * 32 + quad * 8);
        p = xp1[0]; q = xp1[1];
        t.u.x = cvt2(p.x, p.y); t.u.y = cvt2(p.z, p.w);
        t.u.z = cvt2(q.x, q.y); t.u.w = cvt2(q.z, q.w);
        a1[kf] = t.f;
    }

    f32x4 acc0[8], acc1[8];
#pragma unroll
    for (int ct = 0; ct < 8; ++ct) {
        acc0[ct] = (f32x4){0.f, 0.f, 0.f, 0.f};
        acc1[ct] = (f32x4){0.f, 0.f, 0.f, 0.f};
    }

#pragma unroll
    for (int ct = 0; ct < 8; ++ct) {
        const unsigned short* wrow = Wb + (size_t)(ct * 16 + m) * D;
#pragma unroll
        for (int kf = 0; kf < 4; ++kf) {
            frag b = *(const frag*)(wrow + kf * 32 + quad * 8);
            acc0[ct] = __builtin_amdgcn_mfma_f32_16x16x32_bf16(a0[kf], b, acc0[ct], 0, 0, 0);
            acc1[ct] = __builtin_amdgcn_mfma_f32_16x16x32_bf16(a1[kf], b, acc1[ct], 0, 0, 0);
        }
    }

    if (full) {
#pragma unroll
        for (int ct = 0; ct < 8; ++ct) {
#pragma unroll
            for (int r = 0; r < 4; ++r) {
                int rr0 = row0 + quad * 4 + r;
                supb[(size_t)rr0 * D + ct * 16 + m] = (unsigned short)bf1(acc0[ct][r]);
                supb[(size_t)(rr0 + 16) * D + ct * 16 + m] = (unsigned short)bf1(acc1[ct][r]);
            }
        }
    } else {
#pragma unroll
        for (int ct = 0; ct < 8; ++ct) {
#pragma unroll
            for (int r = 0; r < 4; ++r) {
                int rr0 = row0 + quad * 4 + r;
                if (rr0 < n_nodes)
                    supb[(size_t)rr0 * D + ct * 16 + m] = (unsigned short)bf1(acc0[ct][r]);
                int rr1 = rr0 + 16;
                if (rr1 < n_nodes)
                    supb[(size_t)rr1 * D + ct * 16 + m] = (unsigned short)bf1(acc1[ct][r]);
            }
        }
    }
}

// ---- pass 1: LDS-staged coarse binning (1024 threads, C1=3200) ----
__global__ __launch_bounds__(BT) void binpass_kernel(const int* __restrict__ erow,
                                                     const int* __restrict__ ecol,
                                                     const float* __restrict__ eval,
                                                     int* __restrict__ gcursor,
                                                     int2* __restrict__ coarse,
                                                     int n_edges, int nb) {
    __shared__ int bkcnt[NBMAX];
    __shared__ int bkoff[NBMAX];
    __shared__ int wsum[16];
    __shared__ int gbase[NBMAX];
    __shared__ unsigned short slotbk[C1];
    __shared__ int2 stage[C1];
    const int t = threadIdx.x;
    const int base = blockIdx.x * C1;
    const int m = min(C1, n_edges - base);

    for (int i = t; i < nb; i += BT) bkcnt[i] = 0;
    __syncthreads();

    constexpr int EPT = (C1 + BT - 1) / BT;  // 4 (last partially used)
    int  bk[EPT], rank[EPT];
    int2 pk[EPT];
#pragma unroll
    for (int j = 0; j < EPT; ++j) {
        int i = t + j * BT;              // coalesced
        bk[j] = -1;
        if (i < m) {
            int e = base + i;
            int dst = erow[e];
            int b = dst / NPB;
            bk[j] = b;
            rank[j] = atomicAdd(&bkcnt[b], 1);
            pk[j] = make_int2(ecol[e] | ((dst & (NPB - 1)) << 20),
                              __float_as_int(eval[e]));
        }
    }
    __syncthreads();

    // hierarchical exclusive scan of bkcnt[0..nb): 2 barriers total
    {
        const int w = t >> 6, l = t & 63;
        int v = (t < nb) ? bkcnt[t] : 0;
        int inc = v;                      // 64-lane inclusive shuffle scan
#pragma unroll
        for (int o = 1; o < 64; o <<= 1) {
            int u = __shfl_up(inc, o, 64);
            if (l >= o) inc += u;
        }
        if (l == 63) wsum[w] = inc;
        __syncthreads();
        if (t < 16) {                     // scan the 16 wave totals
            int wv2 = wsum[t];
            int winc = wv2;
#pragma unroll
            for (int o = 1; o < 16; o <<= 1) {
                int u = __shfl_up(winc, o, 16);
                if (t >= o) winc += u;
            }
            wsum[t] = winc - wv2;         // exclusive wave prefix
        }
        __syncthreads();
        if (t < nb) bkoff[t] = inc - v + wsum[w];
    }
    __syncthreads();

    // place into stage (LDS scatter) + record slot->bucket
#pragma unroll
    for (int j = 0; j < EPT; ++j) {
        if (bk[j] >= 0) {
            int s = bkoff[bk[j]] + rank[j];
            stage[s] = pk[j];
            slotbk[s] = (unsigned short)bk[j];
        }
    }
    // reserve global runs: one atomic per non-empty bucket
    if (t < nb) {
        int c = bkcnt[t];
        gbase[t] = (c > 0) ? (t * CAP + atomicAdd(&gcursor[t], c)) : 0;
    }
    __syncthreads();

    // copy runs out (consecutive slots in a bucket -> consecutive global addrs)
    for (int i = t; i < m; i += BT) {
        int b = slotbk[i];
        int p = gbase[b] + (i - bkoff[b]);
        if (p < (b + 1) * CAP) coarse[p] = stage[i];   // clamp: never hit here
    }
}

// ---- pass 2: within-bucket exact sort in LDS + quarter-wave fused gather ----
__global__ __launch_bounds__(BT) void sortgather_kernel(const int* __restrict__ gcursor,
                                                        const int2* __restrict__ coarse,
                                                        const unsigned short* __restrict__ supb,
                                                        const float* __restrict__ bias,
                                                        float* __restrict__ out,
                                                        int n_nodes) {
    __shared__ int ncnt[NPB];
    __shared__ int noff[NPB];
    __shared__ int ncur[NPB];
    __shared__ int2 sorted[CAP];
    const int t = threadIdx.x;
    const int b = blockIdx.x;
    const int node0 = b * NPB;
    const int m = min(gcursor[b], CAP);
    const int2* src = coarse + (size_t)b * CAP;

    if (t < NPB) ncnt[t] = 0;
    __syncthreads();

    // read edges once into registers; count
    constexpr int EPT2 = CAP / BT;        // 2
    int2 ee[EPT2];
    int  dl[EPT2];
#pragma unroll
    for (int j = 0; j < EPT2; ++j) {
        int i = t + j * BT;
        dl[j] = -1;
        if (i < m) {
            ee[j] = src[i];
            dl[j] = (ee[j].x >> 20) & (NPB - 1);
            atomicAdd(&ncnt[dl[j]], 1);
        }
    }
    __syncthreads();

    if (t < NPB) {                        // wave 0: 64-lane inclusive shuffle scan
        int v = ncnt[t];
        int inc = v;
        for (int o = 1; o < NPB; o <<= 1) {
            int u = __shfl_up(inc, o, 64);
            if (t >= o) inc += u;
        }
        noff[t] = inc - v;
        ncur[t] = inc - v;
    }
    __syncthreads();

#pragma unroll
    for (int j = 0; j < EPT2; ++j) {      // place into sorted LDS slots
        if (dl[j] >= 0) {
            int p = atomicAdd(&ncur[dl[j]], 1);
            sorted[p] = make_int2(ee[j].x & 0xFFFFF, ee[j].y);
        }
    }
    __syncthreads();

    // gather: 64 quarter-waves <-> 64 nodes; 16 lanes x 8 cols (uint4 = 8 bf16)
    const int qw = t >> 4;               // dst-local node id, 0..63
    const int l16 = t & 15;              // lane within quarter-wave
    const int node = node0 + qw;
    if (node >= n_nodes) return;
    const int beg = noff[qw];
    const int end = beg + ncnt[qw];

    const float4* b4 = (const float4*)(bias + l16 * 8);
    float4 acc0 = b4[0], acc1 = b4[1];

    int e = beg;
    for (; e + 3 < end; e += 4) {         // 4 outstanding supb loads
        int2 d0 = sorted[e], d1 = sorted[e + 1], d2 = sorted[e + 2], d3 = sorted[e + 3];
        uint4 u0 = *(const uint4*)(supb + (size_t)d0.x * D + l16 * 8);
        uint4 u1 = *(const uint4*)(supb + (size_t)d1.x * D + l16 * 8);
        uint4 u2 = *(const uint4*)(supb + (size_t)d2.x * D + l16 * 8);
        uint4 u3 = *(const uint4*)(supb + (size_t)d3.x * D + l16 * 8);
        float v0 = __int_as_float(d0.y), v1 = __int_as_float(d1.y);
        float v2 = __int_as_float(d2.y), v3 = __int_as_float(d3.y);
        acc0.x += v0 * bflo(u0.x) + v1 * bflo(u1.x) + v2 * bflo(u2.x) + v3 * bflo(u3.x);
        acc0.y += v0 * bfhi(u0.x) + v1 * bfhi(u1.x) + v2 * bfhi(u2.x) + v3 * bfhi(u3.x);
        acc0.z += v0 * bflo(u0.y) + v1 * bflo(u1.y) + v2 * bflo(u2.y) + v3 * bflo(u3.y);
        acc0.w += v0 * bfhi(u0.y) + v1 * bfhi(u1.y) + v2 * bfhi(u2.y) + v3 * bfhi(u3.y);
        acc1.x += v0 * bflo(u0.z) + v1 * bflo(u1.z) + v2 * bflo(u2.z) + v3 * bflo(u3.z);
        acc1.y += v0 * bfhi(u0.z) + v1 * bfhi(u1.z) + v2 * bfhi(u2.z) + v3 * bfhi(u3.z);
        acc1.z += v0 * bflo(u0.w) + v1 * bflo(u1.w) + v2 * bflo(u2.w) + v3 * bflo(u3.w);
        acc1.w += v0 * bfhi(u0.w) + v1 * bfhi(u1.w) + v2 * bfhi(u2.w) + v3 * bfhi(u3.w);
    }
    for (; e < end; ++e) {
        int2 d0 = sorted[e];
        uint4 u0 = *(const uint4*)(supb + (size_t)d0.x * D + l16 * 8);
        float v0 = __int_as_float(d0.y);
        acc0.x += v0 * bflo(u0.x); acc0.y += v0 * bfhi(u0.x);
        acc0.z += v0 * bflo(u0.y); acc0.w += v0 * bfhi(u0.y);
        acc1.x += v0 * bflo(u0.z); acc1.y += v0 * bfhi(u0.z);
        acc1.z += v0 * bflo(u0.w); acc1.w += v0 * bfhi(u0.w);
    }
    float4* o4 = (float4*)(out + (size_t)node * D + l16 * 8);
    o4[0] = acc0;
    o4[1] = acc1;
}

// ---- fallback (oversized graphs / tiny ws): atomic path ----
__global__ __launch_bounds__(256) void init_out_kernel(float4* __restrict__ out4,
                                                       const float4* __restrict__ bias4,
                                                       int total4) {
    int i = blockIdx.x * 256 + threadIdx.x;
    if (i < total4) out4[i] = bias4[i & 31];
}

__global__ __launch_bounds__(256) void scatter_fb_kernel(const int* __restrict__ erow,
                                                         const int* __restrict__ ecol,
                                                         const float* __restrict__ eval,
                                                         const unsigned short* __restrict__ supb,
                                                         float* __restrict__ out,
                                                         int n_edges) {
    int e = blockIdx.x * 8 + (threadIdx.x >> 5);
    if (e >= n_edges) return;
    int lane = threadIdx.x & 31;
    int src = ecol[e], dst = erow[e];
    float v = eval[e];
    const unsigned short* sp = supb + (size_t)src * D + lane * 4;
    float* op = out + (size_t)dst * D + lane * 4;
#pragma unroll
    for (int j = 0; j < 4; ++j)
        atomicAdd(op + j, v * __uint_as_float(((unsigned)sp[j]) << 16));
}

static inline size_t align_up(size_t v, size_t a) { return (v + a - 1) & ~(a - 1); }

extern "C" void kernel_launch(void* const* d_in, const int* in_sizes, int n_in,
                              void* d_out, int out_size, void* d_ws, size_t ws_size,
                              hipStream_t stream) {
    const float* x    = (const float*)d_in[0];
    const int*   erow = (const int*)d_in[1];
    const int*   ecol = (const int*)d_in[2];
    const float* eval = (const float*)d_in[3];
    const float* W    = (const float*)d_in[4];
    const float* bias = (const float*)d_in[5];
    float* out = (float*)d_out;

    const int n_nodes = in_sizes[0] / D;
    const int n_edges = in_sizes[1];
    const int nb = (n_nodes + NPB - 1) / NPB;

    char* base = (char*)d_ws;
    size_t off = 0;
    unsigned short* supb = (unsigned short*)(base + off); off = align_up(off + (size_t)n_nodes * D * 2, 256);
    unsigned short* Wb   = (unsigned short*)(base + off); off = align_up(off + (size_t)D * D * 2, 256);
    int*  gcursor = (int*)(base + off);  off = align_up(off + (size_t)nb * 4, 256);
    int2* coarse  = (int2*)(base + off); off = align_up(off + (size_t)nb * CAP * 8, 256);

    const int n8 = D * D / 8;
    const int cvt_grid = (max(n8, nb) + 255) / 256;
    const bool fast = (n_nodes < (1 << 20)) && (nb <= NBMAX) && (off <= ws_size);

    cvt_bf16_kernel<<<cvt_grid, 256, 0, stream>>>(W, (uint4*)Wb, n8, gcursor, fast ? nb : 0);
    gemm_mfma_kernel<<<(n_nodes + 127) / 128, 256, 0, stream>>>(x, Wb, supb, n_nodes);

    if (fast) {
        binpass_kernel<<<(n_edges + C1 - 1) / C1, BT, 0, stream>>>(
            erow, ecol, eval, gcursor, coarse, n_edges, nb);
        sortgather_kernel<<<nb, BT, 0, stream>>>(
            gcursor, coarse, supb, bias, out, n_nodes);
    } else {
        int total4 = n_nodes * (D / 4);
        init_out_kernel<<<(total4 + 255) / 256, 256, 0, stream>>>(
            (float4*)out, (const float4*)bias, total4);
        scatter_fb_kernel<<<(n_edges + 7) / 8, 256, 0, stream>>>(
            erow, ecol, eval, supb, out, n_edges);
    }
}